// Round 4
// baseline (288.590 us; speedup 1.0000x reference)
//
#include <hip/hip_runtime.h>
#include <stdint.h>

typedef _Float16 f16;
typedef _Float16 half8 __attribute__((ext_vector_type(8)));
typedef float f32x4 __attribute__((ext_vector_type(4)));

#define BATCH 16
#define NQ 64
#define SL 4096
#define DH 128

// Tiled f16 layout for Kt/Vt, per b (halves):
//   off(d, n) = (n>>5)*4096 + (d>>4)*512 + ((n>>3)&3)*128 + (d&15)*8 + (n&7)
// A fragment read (16x16x32 MFMA) is then LDS/global  base + lane*16 bytes.

typedef __attribute__((address_space(3))) uint8_t lds8_t;
typedef __attribute__((address_space(1))) uint8_t glb8_t;

__device__ __forceinline__ void gload16(const void* g, void* l) {
  __builtin_amdgcn_global_load_lds((const glb8_t*)g, (lds8_t*)l, 16, 0, 0);
}

// ---------------------------------------------------------------------------
// Kernel P: convert f32 [b][n][d] -> f16 tiled [b][(d,n) tiled]
// ---------------------------------------------------------------------------
__global__ __launch_bounds__(256) void kprep(const float* __restrict__ Kg,
                                             const float* __restrict__ Vg,
                                             f16* __restrict__ Kt,
                                             f16* __restrict__ Vt) {
  __shared__ f16 Ld[128][130];
  const int blk = blockIdx.x;
  const int b = blk >> 6;
  const int tensor = (blk >> 5) & 1;
  const int chunk = blk & 31;
  const float* src = tensor ? Vg : Kg;
  f16* dst = tensor ? Vt : Kt;
  const int t = threadIdx.x;
  const int n0 = chunk * 128;
  {
    const int d = t & 127;
    const int nl = t >> 7;  // 0..1
    const float* s = src + ((size_t)b * SL + n0 + nl) * DH + d;
    for (int it = 0; it < 64; ++it)
      Ld[d][nl + it * 2] = (f16)s[(size_t)it * 2 * DH];
  }
  __syncthreads();
  {
    const int r = t & 15;
    const int kc = (t >> 4) & 3;
    const int w = t >> 6;
    char* dstb = (char*)(dst + (size_t)b * DH * SL);
#pragma unroll
    for (int tl = 0; tl < 4; ++tl)
#pragma unroll
      for (int hh = 0; hh < 2; ++hh) {
        const int dhi = w + hh * 4;
        const int d = dhi * 16 + r;
        const int nl = tl * 32 + kc * 8;
        const half8 v = *(const half8*)&Ld[d][nl];
        *(half8*)(dstb + (size_t)(chunk * 4 + tl) * 8192 + dhi * 1024 +
                  kc * 256 + r * 16) = v;
      }
  }
}

// ---------------------------------------------------------------------------
// Kernel S: E[b][q][n] = (f16)exp(scale * Q.K[n]).  Reads tiled Kt.
// ---------------------------------------------------------------------------
__global__ __launch_bounds__(256) void kscore(const float* __restrict__ Q,
                                              const f16* __restrict__ Kt,
                                              f16* __restrict__ E) {
  __shared__ float Qs[8][128];
  const int blk = blockIdx.x;
  const int b = blk >> 5;
  const int qg = (blk >> 2) & 7;
  const int ns = blk & 3;
  const int t = threadIdx.x;
  for (int i = t; i < 8 * 128; i += 256)
    Qs[i >> 7][i & 127] = Q[((size_t)b * NQ + qg * 8 + (i >> 7)) * DH + (i & 127)];
  __syncthreads();
  const int w = t >> 6, l = t & 63;
  const int q0 = (w >> 1) * 4;
  const int nbase = ns * 1024 + (w & 1) * 512 + l * 8;
  const f16* kb = Kt + (size_t)b * DH * SL + (size_t)(nbase >> 5) * 4096 +
                  (size_t)((nbase >> 3) & 3) * 128;
  float acc[4][8] = {};
  for (int d = 0; d < DH; ++d) {
    const half8 kv = *(const half8*)(kb + (d >> 4) * 512 + (d & 15) * 8);
    float kf[8];
#pragma unroll
    for (int j = 0; j < 8; ++j) kf[j] = (float)kv[j];
#pragma unroll
    for (int qi = 0; qi < 4; ++qi) {
      const float qv = Qs[q0 + qi][d];
#pragma unroll
      for (int j = 0; j < 8; ++j) acc[qi][j] += qv * kf[j];
    }
  }
  const float scl = 0.08838834764831845f;  // 1/sqrt(128)
#pragma unroll
  for (int qi = 0; qi < 4; ++qi) {
    half8 ev;
#pragma unroll
    for (int j = 0; j < 8; ++j) ev[j] = (f16)__expf(acc[qi][j] * scl);
    *(half8*)&E[((size_t)b * NQ + qg * 8 + q0 + qi) * SL + nbase] = ev;
  }
}

// ---------------------------------------------------------------------------
// Kernel R: denom[b][q] = sum_n E[b][q][n] (f16 in, f32 acc, deterministic)
// ---------------------------------------------------------------------------
__global__ __launch_bounds__(256) void kreduce(const f16* __restrict__ E,
                                               float* __restrict__ denom) {
  const int gw = blockIdx.x * 4 + (threadIdx.x >> 6);
  const int lane = threadIdx.x & 63;
  const f16* e = E + (size_t)gw * SL;
  float s = 0.f;
#pragma unroll
  for (int i = 0; i < 8; ++i) {
    const half8 h = *(const half8*)(e + i * 512 + lane * 8);
#pragma unroll
    for (int j = 0; j < 8; ++j) s += (float)h[j];
  }
  for (int off = 1; off < 64; off <<= 1) s += __shfl_xor(s, off);
  if (lane == 0) denom[gw] = s;
}

// ---------------------------------------------------------------------------
// Kernel EVK: EVp[nh][b][q][v] = sum_{n in half} E*V (and EK) via MFMA.
// grid 128 = b(16)*tensor(2)*qh(2)*nh(2); block 256 (4 waves).
// wave w covers row-subtiles {w, w+4}; partials summed in kjac epilogue.
// ---------------------------------------------------------------------------
__global__ __launch_bounds__(256) void kev(const f16* __restrict__ Vt,
                                           const f16* __restrict__ Kt,
                                           const f16* __restrict__ E,
                                           float* __restrict__ EVp,
                                           float* __restrict__ EKp) {
  const int blk = blockIdx.x;
  const int b = blk >> 3;
  const int tensor = (blk >> 2) & 1;
  const int qh = (blk >> 1) & 1;
  const int nh = blk & 1;
  const char* src = (const char*)((tensor ? Kt : Vt) + (size_t)b * DH * SL);
  float* dst = (tensor ? EKp : EVp) +
               ((size_t)nh * BATCH * NQ + (size_t)b * NQ + qh * 32) * DH;
  const f16* Eb = E + ((size_t)b * NQ + qh * 32) * SL;
  const int t = threadIdx.x, w = t >> 6, l = t & 63;
  f32x4 acc[2][2] = {};
  for (int n0 = nh * 2048; n0 < nh * 2048 + 2048; n0 += 32) {
    const half8 a0 =
        *(const half8*)(src + (size_t)(n0 >> 5) * 8192 + w * 1024 + l * 16);
    const half8 a1 =
        *(const half8*)(src + (size_t)(n0 >> 5) * 8192 + (w + 4) * 1024 + l * 16);
    const half8 b0 = *(const half8*)(Eb + (size_t)(l & 15) * SL + n0 + (l >> 4) * 8);
    const half8 b1 =
        *(const half8*)(Eb + (size_t)((l & 15) + 16) * SL + n0 + (l >> 4) * 8);
    acc[0][0] = __builtin_amdgcn_mfma_f32_16x16x32_f16(a0, b0, acc[0][0], 0, 0, 0);
    acc[0][1] = __builtin_amdgcn_mfma_f32_16x16x32_f16(a0, b1, acc[0][1], 0, 0, 0);
    acc[1][0] = __builtin_amdgcn_mfma_f32_16x16x32_f16(a1, b0, acc[1][0], 0, 0, 0);
    acc[1][1] = __builtin_amdgcn_mfma_f32_16x16x32_f16(a1, b1, acc[1][1], 0, 0, 0);
  }
#pragma unroll
  for (int sv2 = 0; sv2 < 2; ++sv2)
#pragma unroll
    for (int qj = 0; qj < 2; ++qj) {
      const int q = qj * 16 + (l & 15);
      const int row = (w + sv2 * 4) * 16 + (l >> 4) * 4;
      *(f32x4*)&dst[(size_t)q * DH + row] = acc[sv2][qj];
    }
}

// ---------------------------------------------------------------------------
// Kernel G: per (b, 2 q):  T[v][k] = sum_n (E_n*V[n,v]) * K[n,k]  via MFMA.
// BK=64, double-buffered gload_lds staging, COUNTED vmcnt (never 0 in loop),
// raw s_barrier, E prefetched into regs one tile ahead, setprio on MFMA.
// out = scale*invd*(T - invd*EV[v]*EK[k]).
// ---------------------------------------------------------------------------
__global__ __launch_bounds__(256, 2) void kjac(
    const f16* __restrict__ Vt, const f16* __restrict__ Kt,
    const f16* __restrict__ E, const float* __restrict__ EV,
    const float* __restrict__ EK, const float* __restrict__ denom,
    float* __restrict__ out) {
  __shared__ __align__(16) f16 Vl[2][8192];
  __shared__ __align__(16) f16 Kl[2][8192];

  const int blk = blockIdx.x;
  const int b = blk >> 5;
  const int q0 = (blk & 31) * 2;
  const int t = threadIdx.x, w = t >> 6, l = t & 63;
  const int sA = (w >> 1) * 4;  // A row-subtile base (quadrant)
  const int sB = (w & 1) * 4;   // B col-subtile base
  const char* vtb = (const char*)(Vt + (size_t)b * DH * SL);
  const char* ktb = (const char*)(Kt + (size_t)b * DH * SL);
  const f16* Eb = E + ((size_t)b * NQ + q0) * SL;

  f32x4 acc[2][4][4] = {};

#define STAGE(tile, buf)                                                     \
  {                                                                          \
    const size_t gb = (size_t)(tile) * 16384 + t * 16;                       \
    _Pragma("unroll") for (int i = 0; i < 4; ++i) {                          \
      gload16(vtb + gb + i * 4096, (char*)Vl[buf] + t * 16 + i * 4096);      \
      gload16(ktb + gb + i * 4096, (char*)Kl[buf] + t * 16 + i * 4096);      \
    }                                                                        \
  }

#define PRELOAD(dst, tt)                                                     \
  {                                                                          \
    const int nn = (tt) * 64 + (l >> 4) * 8;                                 \
    dst[0][0] = *(const half8*)(Eb + nn);                                    \
    dst[0][1] = *(const half8*)(Eb + nn + 32);                               \
    dst[1][0] = *(const half8*)(Eb + SL + nn);                               \
    dst[1][1] = *(const half8*)(Eb + SL + nn + 32);                          \
  }

#define COMPUTE(buf, e)                                                      \
  _Pragma("unroll") for (int h = 0; h < 2; ++h) {                            \
    const f16* vbuf = Vl[buf] + h * 4096;                                    \
    const f16* kbuf = Kl[buf] + h * 4096;                                    \
    half8 vf[4], kf[4];                                                      \
    _Pragma("unroll") for (int i = 0; i < 4; ++i) vf[i] =                    \
        *(const half8*)(vbuf + (sA + i) * 512 + l * 8);                      \
    _Pragma("unroll") for (int j = 0; j < 4; ++j) kf[j] =                    \
        *(const half8*)(kbuf + (sB + j) * 512 + l * 8);                      \
    __builtin_amdgcn_s_setprio(1);                                           \
    _Pragma("unroll") for (int i = 0; i < 4; ++i) {                          \
      const half8 u0 = e[0][h] * vf[i];                                      \
      const half8 u1 = e[1][h] * vf[i];                                      \
      _Pragma("unroll") for (int j = 0; j < 4; ++j) {                        \
        acc[0][i][j] = __builtin_amdgcn_mfma_f32_16x16x32_f16(               \
            u0, kf[j], acc[0][i][j], 0, 0, 0);                               \
        acc[1][i][j] = __builtin_amdgcn_mfma_f32_16x16x32_f16(               \
            u1, kf[j], acc[1][i][j], 0, 0, 0);                               \
      }                                                                      \
    }                                                                        \
    __builtin_amdgcn_s_setprio(0);                                           \
  }

  half8 eA[2][2], eB[2][2];
  PRELOAD(eA, 0)
  STAGE(0, 0)
  for (int tt = 0; tt < 64; tt += 2) {
    PRELOAD(eB, tt + 1)
    STAGE(tt + 1, 1)
    asm volatile("s_waitcnt vmcnt(12)" ::: "memory");
    __builtin_amdgcn_s_barrier();
    COMPUTE(0, eA)
    __builtin_amdgcn_s_barrier();
    if (tt + 2 < 64) {
      PRELOAD(eA, tt + 2)
      STAGE(tt + 2, 0)
      asm volatile("s_waitcnt vmcnt(12)" ::: "memory");
    } else {
      asm volatile("s_waitcnt vmcnt(0)" ::: "memory");
    }
    __builtin_amdgcn_s_barrier();
    COMPUTE(1, eB)
    __builtin_amdgcn_s_barrier();
  }
#undef STAGE
#undef PRELOAD
#undef COMPUTE

  const float scl = 0.08838834764831845f;
#pragma unroll
  for (int q = 0; q < 2; ++q) {
    const float invd = 1.0f / denom[b * NQ + q0 + q];
    const float* evq = EV + ((size_t)b * NQ + q0 + q) * DH;
    const float* evq2 = evq + (size_t)BATCH * NQ * DH;
    const float* ekq = EK + ((size_t)b * NQ + q0 + q) * DH;
    const float* ekq2 = ekq + (size_t)BATCH * NQ * DH;
    float* ob = out + (size_t)(b * NQ + q0 + q) * DH * DH;
#pragma unroll
    for (int i = 0; i < 4; ++i) {
      const int row0 = (sA + i) * 16 + (l >> 4) * 4;
      const f32x4 ev4 = *(const f32x4*)&evq[row0] + *(const f32x4*)&evq2[row0];
#pragma unroll
      for (int j = 0; j < 4; ++j) {
        const int col = (sB + j) * 16 + (l & 15);
        const float ek = ekq[col] + ekq2[col];
#pragma unroll
        for (int r = 0; r < 4; ++r)
          ob[(size_t)(row0 + r) * DH + col] =
              scl * invd * (acc[q][i][j][r] - invd * ev4[r] * ek);
      }
    }
  }
}

extern "C" void kernel_launch(void* const* d_in, const int* in_sizes, int n_in,
                              void* d_out, int out_size, void* d_ws,
                              size_t ws_size, hipStream_t stream) {
  const float* Q = (const float*)d_in[0];
  const float* K = (const float*)d_in[1];
  const float* V = (const float*)d_in[2];
  float* out = (float*)d_out;

  // ws: Vt 16.8MB | Kt 16.8MB | E f16 8.4MB | EVp 1MB | EKp 1MB | denom 4KB
  f16* Vt = (f16*)d_ws;
  f16* Kt = Vt + (size_t)BATCH * DH * SL;
  f16* Ef = Kt + (size_t)BATCH * DH * SL;
  float* EV = (float*)(Ef + (size_t)BATCH * NQ * SL);
  float* EK = EV + 2 * (size_t)BATCH * NQ * DH;
  float* denom = EK + 2 * (size_t)BATCH * NQ * DH;

  kprep<<<1024, 256, 0, stream>>>(K, V, Kt, Vt);
  kscore<<<512, 256, 0, stream>>>(Q, Kt, Ef);
  kreduce<<<256, 256, 0, stream>>>(Ef, denom);
  kev<<<128, 256, 0, stream>>>(Vt, Kt, Ef, EV, EK);
  kjac<<<512, 256, 0, stream>>>(Vt, Kt, Ef, EV, EK, denom, out);
}

// Round 5
// 193.827 us; speedup vs baseline: 1.4889x; 1.4889x over previous
//
#include <hip/hip_runtime.h>
#include <stdint.h>

typedef _Float16 f16;
typedef _Float16 half8 __attribute__((ext_vector_type(8)));
typedef float f32x4 __attribute__((ext_vector_type(4)));

#define BATCH 16
#define NQ 64
#define SL 4096
#define DH 128

// Tiled f16 layout for Kt/Vt, per b (halves):
//   off(d, n) = (n>>5)*4096 + (d>>4)*512 + ((n>>3)&3)*128 + (d&15)*8 + (n&7)
// A fragment read (16x16x32 MFMA) is then LDS/global  base + lane*16 bytes.

typedef __attribute__((address_space(3))) uint8_t lds8_t;
typedef __attribute__((address_space(1))) uint8_t glb8_t;

__device__ __forceinline__ void gload16(const void* g, void* l) {
  __builtin_amdgcn_global_load_lds((const glb8_t*)g, (lds8_t*)l, 16, 0, 0);
}

// ---------------------------------------------------------------------------
// Kernel P: convert f32 [b][n][d] -> f16 tiled [b][(d,n) tiled]
// ---------------------------------------------------------------------------
__global__ __launch_bounds__(256) void kprep(const float* __restrict__ Kg,
                                             const float* __restrict__ Vg,
                                             f16* __restrict__ Kt,
                                             f16* __restrict__ Vt) {
  __shared__ f16 Ld[128][130];
  const int blk = blockIdx.x;
  const int b = blk >> 6;
  const int tensor = (blk >> 5) & 1;
  const int chunk = blk & 31;
  const float* src = tensor ? Vg : Kg;
  f16* dst = tensor ? Vt : Kt;
  const int t = threadIdx.x;
  const int n0 = chunk * 128;
  {
    const int d = t & 127;
    const int nl = t >> 7;  // 0..1
    const float* s = src + ((size_t)b * SL + n0 + nl) * DH + d;
    for (int it = 0; it < 64; ++it)
      Ld[d][nl + it * 2] = (f16)s[(size_t)it * 2 * DH];
  }
  __syncthreads();
  {
    const int r = t & 15;
    const int kc = (t >> 4) & 3;
    const int w = t >> 6;
    char* dstb = (char*)(dst + (size_t)b * DH * SL);
#pragma unroll
    for (int tl = 0; tl < 4; ++tl)
#pragma unroll
      for (int hh = 0; hh < 2; ++hh) {
        const int dhi = w + hh * 4;
        const int d = dhi * 16 + r;
        const int nl = tl * 32 + kc * 8;
        const half8 v = *(const half8*)&Ld[d][nl];
        *(half8*)(dstb + (size_t)(chunk * 4 + tl) * 8192 + dhi * 1024 +
                  kc * 256 + r * 16) = v;
      }
  }
}

// ---------------------------------------------------------------------------
// Kernel S: E[b][q][n] = (f16)exp(scale * Q.K[n]).  Reads tiled Kt.
// XCD-swizzled blockIdx (512 blocks, 64/XCD -> 2 b's per XCD L2).
// ---------------------------------------------------------------------------
__global__ __launch_bounds__(256) void kscore(const float* __restrict__ Q,
                                              const f16* __restrict__ Kt,
                                              f16* __restrict__ E) {
  const int blk = (blockIdx.x & 7) * 64 + (blockIdx.x >> 3);
  __shared__ float Qs[8][128];
  const int b = blk >> 5;
  const int qg = (blk >> 2) & 7;
  const int ns = blk & 3;
  const int t = threadIdx.x;
  for (int i = t; i < 8 * 128; i += 256)
    Qs[i >> 7][i & 127] = Q[((size_t)b * NQ + qg * 8 + (i >> 7)) * DH + (i & 127)];
  __syncthreads();
  const int w = t >> 6, l = t & 63;
  const int q0 = (w >> 1) * 4;
  const int nbase = ns * 1024 + (w & 1) * 512 + l * 8;
  const f16* kb = Kt + (size_t)b * DH * SL + (size_t)(nbase >> 5) * 4096 +
                  (size_t)((nbase >> 3) & 3) * 128;
  float acc[4][8] = {};
  for (int d = 0; d < DH; ++d) {
    const half8 kv = *(const half8*)(kb + (d >> 4) * 512 + (d & 15) * 8);
    float kf[8];
#pragma unroll
    for (int j = 0; j < 8; ++j) kf[j] = (float)kv[j];
#pragma unroll
    for (int qi = 0; qi < 4; ++qi) {
      const float qv = Qs[q0 + qi][d];
#pragma unroll
      for (int j = 0; j < 8; ++j) acc[qi][j] += qv * kf[j];
    }
  }
  const float scl = 0.08838834764831845f;  // 1/sqrt(128)
#pragma unroll
  for (int qi = 0; qi < 4; ++qi) {
    half8 ev;
#pragma unroll
    for (int j = 0; j < 8; ++j) ev[j] = (f16)__expf(acc[qi][j] * scl);
    *(half8*)&E[((size_t)b * NQ + qg * 8 + q0 + qi) * SL + nbase] = ev;
  }
}

// ---------------------------------------------------------------------------
// Kernel R: denom[b][q] = sum_n E[b][q][n] (f16 in, f32 acc, deterministic)
// ---------------------------------------------------------------------------
__global__ __launch_bounds__(256) void kreduce(const f16* __restrict__ E,
                                               float* __restrict__ denom) {
  const int gw = blockIdx.x * 4 + (threadIdx.x >> 6);
  const int lane = threadIdx.x & 63;
  const f16* e = E + (size_t)gw * SL;
  float s = 0.f;
#pragma unroll
  for (int i = 0; i < 8; ++i) {
    const half8 h = *(const half8*)(e + i * 512 + lane * 8);
#pragma unroll
    for (int j = 0; j < 8; ++j) s += (float)h[j];
  }
  for (int off = 1; off < 64; off <<= 1) s += __shfl_xor(s, off);
  if (lane == 0) denom[gw] = s;
}

// ---------------------------------------------------------------------------
// Kernel EVK: EVp[nh][b][q][v] = sum_{n in half} E*V (and EK) via MFMA.
// grid 256 = b(16)*tensor(2)*qq(4; 16 q each)*nh(2); 1 block/CU.
// wave w covers row-subtiles {w, w+4}; partials summed in kjac epilogue.
// ---------------------------------------------------------------------------
__global__ __launch_bounds__(256) void kev(const f16* __restrict__ Vt,
                                           const f16* __restrict__ Kt,
                                           const f16* __restrict__ E,
                                           float* __restrict__ EVp,
                                           float* __restrict__ EKp) {
  const int blk = (blockIdx.x & 7) * 32 + (blockIdx.x >> 3);
  const int b = blk >> 4;
  const int tensor = (blk >> 3) & 1;
  const int qq = (blk >> 1) & 3;
  const int nh = blk & 1;
  const char* src = (const char*)((tensor ? Kt : Vt) + (size_t)b * DH * SL);
  float* dst = (tensor ? EKp : EVp) +
               ((size_t)nh * BATCH * NQ + (size_t)b * NQ + qq * 16) * DH;
  const f16* Eb = E + ((size_t)b * NQ + qq * 16) * SL;
  const int t = threadIdx.x, w = t >> 6, l = t & 63;
  f32x4 acc[2] = {};
  for (int n0 = nh * 2048; n0 < nh * 2048 + 2048; n0 += 32) {
    const half8 a0 =
        *(const half8*)(src + (size_t)(n0 >> 5) * 8192 + w * 1024 + l * 16);
    const half8 a1 =
        *(const half8*)(src + (size_t)(n0 >> 5) * 8192 + (w + 4) * 1024 + l * 16);
    const half8 b0 =
        *(const half8*)(Eb + (size_t)(l & 15) * SL + n0 + (l >> 4) * 8);
    acc[0] = __builtin_amdgcn_mfma_f32_16x16x32_f16(a0, b0, acc[0], 0, 0, 0);
    acc[1] = __builtin_amdgcn_mfma_f32_16x16x32_f16(a1, b0, acc[1], 0, 0, 0);
  }
#pragma unroll
  for (int sv2 = 0; sv2 < 2; ++sv2) {
    const int q = l & 15;
    const int row = (w + sv2 * 4) * 16 + (l >> 4) * 4;
    *(f32x4*)&dst[(size_t)q * DH + row] = acc[sv2];
  }
}

// ---------------------------------------------------------------------------
// Kernel G: per (b, 2 q):  T[v][k] = sum_n (E_n*V[n,v]) * K[n,k]  via MFMA.
// BK=32, 4 LDS buffers, prefetch distance 2 (S(t+1),S(t+2) in flight),
// counted vmcnt (exact tail ladder), raw s_barrier, E ping-pong 1 ahead,
// setprio on MFMA cluster.  out = scale*invd*(T - invd*EV[v]*EK[k]).
// ---------------------------------------------------------------------------
__global__ __launch_bounds__(256, 2) void kjac(
    const f16* __restrict__ Vt, const f16* __restrict__ Kt,
    const f16* __restrict__ E, const float* __restrict__ EV,
    const float* __restrict__ EK, const float* __restrict__ denom,
    float* __restrict__ out) {
  __shared__ __align__(16) f16 Vl[4][4096];
  __shared__ __align__(16) f16 Kl[4][4096];

  const int blk = (blockIdx.x & 7) * 64 + (blockIdx.x >> 3);  // XCD swizzle
  const int b = blk >> 5;
  const int q0 = (blk & 31) * 2;
  const int t = threadIdx.x, w = t >> 6, l = t & 63;
  const int sA = (w >> 1) * 4;  // A row-subtile base (quadrant)
  const int sB = (w & 1) * 4;   // B col-subtile base
  const char* vtb = (const char*)(Vt + (size_t)b * DH * SL);
  const char* ktb = (const char*)(Kt + (size_t)b * DH * SL);
  const f16* Eb = E + ((size_t)b * NQ + q0) * SL;

  f32x4 acc[2][4][4] = {};
  half8 eA[2], eB[2];

  // 4 gload_lds per STAGE (V 8KB + K 8KB, 4KB per instr)
#define STAGE(tile)                                                          \
  {                                                                          \
    const int bf = (tile) & 3;                                               \
    const size_t gb = (size_t)(tile) * 8192 + t * 16;                        \
    gload16(vtb + gb, (char*)Vl[bf] + t * 16);                               \
    gload16(vtb + gb + 4096, (char*)Vl[bf] + t * 16 + 4096);                 \
    gload16(ktb + gb, (char*)Kl[bf] + t * 16);                               \
    gload16(ktb + gb + 4096, (char*)Kl[bf] + t * 16 + 4096);                 \
  }

#define ELOAD(dst, tile)                                                     \
  {                                                                          \
    const int nn = (tile) * 32 + (l >> 4) * 8;                               \
    dst[0] = *(const half8*)(Eb + nn);                                       \
    dst[1] = *(const half8*)(Eb + SL + nn);                                  \
  }

#define COMPUTE(tile, e)                                                     \
  {                                                                          \
    const f16* vbuf = Vl[(tile) & 3];                                        \
    const f16* kbuf = Kl[(tile) & 3];                                        \
    half8 vf[4], kf[4];                                                      \
    _Pragma("unroll") for (int i = 0; i < 4; ++i) vf[i] =                    \
        *(const half8*)(vbuf + (sA + i) * 512 + l * 8);                      \
    _Pragma("unroll") for (int j = 0; j < 4; ++j) kf[j] =                    \
        *(const half8*)(kbuf + (sB + j) * 512 + l * 8);                      \
    __builtin_amdgcn_s_setprio(1);                                           \
    _Pragma("unroll") for (int i = 0; i < 4; ++i) {                          \
      const half8 u0 = e[0] * vf[i];                                         \
      const half8 u1 = e[1] * vf[i];                                         \
      _Pragma("unroll") for (int j = 0; j < 4; ++j) {                        \
        acc[0][i][j] = __builtin_amdgcn_mfma_f32_16x16x32_f16(               \
            u0, kf[j], acc[0][i][j], 0, 0, 0);                               \
        acc[1][i][j] = __builtin_amdgcn_mfma_f32_16x16x32_f16(               \
            u1, kf[j], acc[1][i][j], 0, 0, 0);                               \
      }                                                                      \
    }                                                                        \
    __builtin_amdgcn_s_setprio(0);                                           \
  }

  // body t: issue E(t+1)+S(t+2), wait so S(t) done but S(t+1..t+2) in flight
#define BODY(tc, eu, el, wn)                                                 \
  {                                                                          \
    ELOAD(el, (tc) + 1)                                                      \
    STAGE((tc) + 2)                                                          \
    asm volatile("s_waitcnt vmcnt(" #wn ")" ::: "memory");                   \
    __builtin_amdgcn_s_barrier();                                            \
    COMPUTE((tc), eu)                                                        \
    __builtin_amdgcn_s_barrier();                                            \
  }

  ELOAD(eA, 0)
  STAGE(0)
  STAGE(1)
  // issue order per body: E(t+1)[2], S(t+2)[4].  After S(t)'s last load:
  // steady = E(t)2 + S(t+1)4 + E(t+1)2 + S(t+2)4 = 12.  body0 = 10.
  BODY(0, eA, eB, 10)
  BODY(1, eB, eA, 12)
  BODY(2, eA, eB, 12)
  BODY(3, eB, eA, 12)
  for (int tt = 4; tt < 124; tt += 4) {
    BODY(tt + 0, eA, eB, 12)
    BODY(tt + 1, eB, eA, 12)
    BODY(tt + 2, eA, eB, 12)
    BODY(tt + 3, eB, eA, 12)
  }
  BODY(124, eA, eB, 12)
  BODY(125, eB, eA, 12)
  // body 126: uses eA, loads E(127), no stage.  after S(126): E(126)2+S(127)4+E(127)2 = 8
  ELOAD(eB, 127)
  asm volatile("s_waitcnt vmcnt(8)" ::: "memory");
  __builtin_amdgcn_s_barrier();
  COMPUTE(126, eA)
  __builtin_amdgcn_s_barrier();
  // body 127: uses eB, nothing outstanding but E(127): after S(127): E(127)2 = 2
  asm volatile("s_waitcnt vmcnt(2)" ::: "memory");
  __builtin_amdgcn_s_barrier();
  COMPUTE(127, eB)
#undef STAGE
#undef ELOAD
#undef COMPUTE
#undef BODY

  const float scl = 0.08838834764831845f;
#pragma unroll
  for (int q = 0; q < 2; ++q) {
    const float invd = 1.0f / denom[b * NQ + q0 + q];
    const float* evq = EV + ((size_t)b * NQ + q0 + q) * DH;
    const float* evq2 = evq + (size_t)BATCH * NQ * DH;
    const float* ekq = EK + ((size_t)b * NQ + q0 + q) * DH;
    const float* ekq2 = ekq + (size_t)BATCH * NQ * DH;
    float* ob = out + (size_t)(b * NQ + q0 + q) * DH * DH;
#pragma unroll
    for (int i = 0; i < 4; ++i) {
      const int row0 = (sA + i) * 16 + (l >> 4) * 4;
      const f32x4 ev4 = *(const f32x4*)&evq[row0] + *(const f32x4*)&evq2[row0];
#pragma unroll
      for (int j = 0; j < 4; ++j) {
        const int col = (sB + j) * 16 + (l & 15);
        const float ek = ekq[col] + ekq2[col];
#pragma unroll
        for (int r = 0; r < 4; ++r)
          ob[(size_t)(row0 + r) * DH + col] =
              scl * invd * (acc[q][i][j][r] - invd * ev4[r] * ek);
      }
    }
  }
}

extern "C" void kernel_launch(void* const* d_in, const int* in_sizes, int n_in,
                              void* d_out, int out_size, void* d_ws,
                              size_t ws_size, hipStream_t stream) {
  const float* Q = (const float*)d_in[0];
  const float* K = (const float*)d_in[1];
  const float* V = (const float*)d_in[2];
  float* out = (float*)d_out;

  // ws: Vt 16.8MB | Kt 16.8MB | E f16 8.4MB | EVp 1MB | EKp 1MB | denom 4KB
  f16* Vt = (f16*)d_ws;
  f16* Kt = Vt + (size_t)BATCH * DH * SL;
  f16* Ef = Kt + (size_t)BATCH * DH * SL;
  float* EV = (float*)(Ef + (size_t)BATCH * NQ * SL);
  float* EK = EV + 2 * (size_t)BATCH * NQ * DH;
  float* denom = EK + 2 * (size_t)BATCH * NQ * DH;

  kprep<<<1024, 256, 0, stream>>>(K, V, Kt, Vt);
  kscore<<<512, 256, 0, stream>>>(Q, Kt, Ef);
  kreduce<<<256, 256, 0, stream>>>(Ef, denom);
  kev<<<256, 256, 0, stream>>>(Vt, Kt, Ef, EV, EK);
  kjac<<<512, 256, 0, stream>>>(Vt, Kt, Ef, EV, EK, denom, out);
}